// Round 6
// baseline (212.027 us; speedup 1.0000x reference)
//
#include <hip/hip_runtime.h>
#include <hip/hip_bf16.h>
#include <math.h>

typedef __bf16 bf16;
typedef __bf16 bf16x4 __attribute__((ext_vector_type(4)));
typedef __bf16 bf16x8 __attribute__((ext_vector_type(8)));
typedef float f32x4 __attribute__((ext_vector_type(4)));
typedef unsigned int u32;

#define LOG2E 1.44269504f

__device__ inline float fast_exp2(float x) {
#if __has_builtin(__builtin_amdgcn_exp2f)
    return __builtin_amdgcn_exp2f(x);
#else
    return exp2f(x);
#endif
}

// async global->LDS, 16B per lane; LDS dest must be lane-contiguous (tid*16B)
#define GL2LDS(gp, lp) __builtin_amdgcn_global_load_lds( \
    (const __attribute__((address_space(1))) u32*)(gp),  \
    (__attribute__((address_space(3))) u32*)(lp), 16, 0, 0)

// Problem constants: B=64, ORDER=2, S=256, D=256, H=8, HD=32

// ---------------- kernel 1 (fused prologue): xb = bf16(x); Wt; A bitmasks ------
// blocks [0,4096): x->bf16. [4096,5120): W -> bf16 transposed. [5120,5376): pack A.
__global__ void prep_k(const float* __restrict__ x, const float* __restrict__ Wp,
                       const int* __restrict__ A, bf16* __restrict__ xb,
                       bf16* __restrict__ Wt, unsigned* __restrict__ m1,
                       unsigned* __restrict__ m2) {
    int bid = blockIdx.x;
    int tid = threadIdx.x;
    if (bid < 4096) {
        int gid = bid * 256 + tid;              // 1,048,576 groups of 8
        const f32x4* xp = (const f32x4*)x + (size_t)gid * 2;
        f32x4 a = xp[0], b4 = xp[1];
        bf16x8 o;
#pragma unroll
        for (int c = 0; c < 4; ++c) { o[c] = (bf16)a[c]; o[c + 4] = (bf16)b4[c]; }
        ((bf16x8*)xb)[gid] = o;
    } else if (bid < 5120) {
        int gid = (bid - 4096) * 256 + tid;     // 4*256*256 elements
        int k = gid & 255;
        int n = (gid >> 8) & 255;
        int ij = gid >> 16;
        Wt[gid] = (bf16)Wp[(ij * 256 + k) * 256 + n];
    } else {
        int pb = bid - 5120;                    // 256 = ijb*2 + s-half
        int sh = pb & 1;
        int ijb = pb >> 1;                      // b*2+i
        const int* Ab = A + ((size_t)ijb << 16);
        unsigned w1 = 0, w2 = 0;
#pragma unroll 8
        for (int sl = 0; sl < 128; ++sl) {
            int s = sh * 128 + sl;
            int av = Ab[s * 256 + tid];
            unsigned f1 = (av == 2 || av == 4) ? 1u : 0u;
            unsigned f2 = (av == 3 || av == 4) ? 1u : 0u;
            w1 |= f1 << (s & 31);
            w2 |= f2 << (s & 31);
            if ((s & 31) == 31) {
                int kc = s >> 5;
                m1[(ijb * 8 + kc) * 256 + tid] = w1;
                m2[(ijb * 8 + kc) * 256 + tid] = w2;
                w1 = 0; w2 = 0;
            }
        }
    }
}

// ---------------- kernel 2: transposed projection GEMM + scores ----------------
// Computes D[d][s] = (x@W+b)^T directly (swapped MFMA operands), writes Vt
// [ijb][h][d][s] coalesced, and the per-head scores a_s/a_d (x LOG2E).
// grid (128 mt: b,s-half; 4 nt: j,d-half; 2 i), 256 threads, tile 128d x 128s.
__launch_bounds__(256)
__global__ void proj_gemm(const bf16* __restrict__ xb, const bf16* __restrict__ Wt,
                          const float* __restrict__ bp, const float* __restrict__ att_src,
                          const float* __restrict__ att_dst, bf16* __restrict__ Vt,
                          float* __restrict__ asb, float* __restrict__ adb) {
    __shared__ char smem[35840 + 1024];
    bf16* As = (bf16*)smem;            // x tile  [s 128][k 32], contiguous
    bf16* Bs = (bf16*)(smem + 8192);   // Wt tile [d 128][k 32]
    bf16* TL = (bf16*)smem;            // epilogue overlay: [d 128][s stride 140]
    float* attL = (float*)(smem + 35840);   // [which 2][h 4][d 32]

    int tid = threadIdx.x;
    int mt = blockIdx.x, nt = blockIdx.y, i = blockIdx.z;
    int n0 = nt * 128;
    int j = n0 >> 8, d0 = n0 & 255;
    int ij = i * 2 + j;
    int m0 = mt * 128;
    int b = m0 >> 8, shalf = (m0 >> 7) & 1;

    // preload att vectors for this block's 4 heads
    {
        int which = tid >> 7, rest = tid & 127;
        const float* ap = which ? att_dst : att_src;
        attL[tid] = ap[(ij * 8 + (d0 >> 5) + (rest >> 5)) * 32 + (rest & 31)];
    }

    // staging: chunk c -> row c>>2, k-offset (c&3)*8 ; LDS dest = c*16B
    int c0 = tid, c1 = tid + 256;
    int r0 = c0 >> 2, k80 = (c0 & 3) * 8;
    int r1 = c1 >> 2, k81 = (c1 & 3) * 8;
    const bf16* ga0 = xb + (((size_t)((b * 2 + i) * 256 + shalf * 128 + r0)) << 8) + k80;
    const bf16* ga1 = xb + (((size_t)((b * 2 + i) * 256 + shalf * 128 + r1)) << 8) + k81;
    const bf16* gb0 = Wt + (((size_t)(ij * 256 + d0 + r0)) << 8) + k80;
    const bf16* gb1 = Wt + (((size_t)(ij * 256 + d0 + r1)) << 8) + k81;
    bf16* la0 = As + c0 * 8;
    bf16* la1 = As + c1 * 8;
    bf16* lb0 = Bs + c0 * 8;
    bf16* lb1 = Bs + c1 * 8;

    int wave = tid >> 6, lane = tid & 63;
    int wd = (wave & 1) * 64, ws = (wave >> 1) * 64;
    int lrow = lane & 15, quad = lane >> 4;

    f32x4 acc[4][4];   // [dj][sj]
#pragma unroll
    for (int a = 0; a < 4; ++a)
#pragma unroll
        for (int c = 0; c < 4; ++c) acc[a][c] = (f32x4){0.f, 0.f, 0.f, 0.f};

    for (int kc = 0; kc < 8; ++kc) {
        int k0 = kc * 32;
        GL2LDS(ga0 + k0, la0);
        GL2LDS(ga1 + k0, la1);
        GL2LDS(gb0 + k0, lb0);
        GL2LDS(gb1 + k0, lb1);
        __syncthreads();
        bf16x8 wf[4], xf[4];
#pragma unroll
        for (int dj = 0; dj < 4; ++dj)
            wf[dj] = *(const bf16x8*)&Bs[(wd + dj * 16 + lrow) * 32 + quad * 8];
#pragma unroll
        for (int sj = 0; sj < 4; ++sj)
            xf[sj] = *(const bf16x8*)&As[(ws + sj * 16 + lrow) * 32 + quad * 8];
#pragma unroll
        for (int dj = 0; dj < 4; ++dj)
#pragma unroll
            for (int sj = 0; sj < 4; ++sj)
                acc[dj][sj] = __builtin_amdgcn_mfma_f32_16x16x32_bf16(wf[dj], xf[sj], acc[dj][sj], 0, 0, 0);
        __syncthreads();
    }

    // ---- bias + cvt -> TL[d][s] (stride 140: quad offsets spread banks) ----
#pragma unroll
    for (int dj = 0; dj < 4; ++dj) {
#pragma unroll
        for (int r = 0; r < 4; ++r) {
            int dl = wd + dj * 16 + quad * 4 + r;
            float bias = bp[ij * 256 + d0 + dl];
#pragma unroll
            for (int sj = 0; sj < 4; ++sj)
                TL[dl * 140 + ws + sj * 16 + lrow] = (bf16)(acc[dj][sj][r] + bias);
        }
    }
    __syncthreads();

    // ---- Vt store: thread -> (dl = tid>>1, s-half 64) ----
    {
        int dl = tid >> 1, sh64 = (tid & 1) * 64;
        const bf16* src = TL + dl * 140 + sh64;
        bf16* dst = Vt + (((size_t)(ij * 64 + b)) << 16) + (size_t)(d0 + dl) * 256
                    + shalf * 128 + sh64;   // slab per (ij,b) = 8h*32d*256s = <<16
#pragma unroll
        for (int q = 0; q < 16; ++q)
            *(bf16x4*)(dst + q * 4) = *(const bf16x4*)(src + q * 4);
    }

    // ---- scores: thread -> (s = tid&127, which = tid>>7); 4 heads x dot32 ----
    {
        int s = tid & 127, which = tid >> 7;
        const float* av = attL + which * 128;
        float* outp = which ? adb : asb;
#pragma unroll
        for (int hl = 0; hl < 4; ++hl) {
            float accs = 0.f;
#pragma unroll
            for (int d = 0; d < 32; ++d)
                accs += (float)TL[(hl * 32 + d) * 140 + s] * av[hl * 32 + d];
            int hg = (d0 >> 5) + hl;
            outp[((ij * 64 + b) * 8 + hg) * 256 + shalf * 128 + s] = accs * LOG2E;
        }
    }
}

// ---------------- kernel 3: fused attention + order-mean + PReLU ---------------
// grid 512: (b, head-group of 4, t-tile of 64); block owns BOTH orders i=0,1 and
// both convs, so the final h + mean(h) + PReLU happens in-registers (no final_k).
__launch_bounds__(256, 2)
__global__ void attn_k(const bf16* __restrict__ Vt, const unsigned* __restrict__ m1,
                       const unsigned* __restrict__ m2, const float* __restrict__ asb,
                       const float* __restrict__ adb, const float* __restrict__ gbias,
                       const float* __restrict__ prelu_a, float* __restrict__ out) {
    int bid = blockIdx.x;
    int tt = bid & 3, hg = (bid >> 2) & 1, b = bid >> 3;
    int t0 = tt * 64;
    int tid = threadIdx.x, wave = tid >> 6, lane = tid & 63;
    int lrow = lane & 15, quad = lane >> 4;
    int h = hg * 4 + wave;

    __shared__ float    as_l[2][2][4][256];   // [i][conv][wave-head][s]   16 KB
    __shared__ unsigned ml[2][2][8][64];      // [i][conv][kc][t_local]     8 KB
    __shared__ float    l_lds[2][2][4][64];   // [i][conv][wave-head][tl]   4 KB

#pragma unroll
    for (int p = 0; p < 16; ++p) {
        int idx = p * 256 + tid;
        int i = idx >> 11, c = (idx >> 10) & 1, w = (idx >> 8) & 3, s = idx & 255;
        as_l[i][c][w][s] = asb[(((i * 2 + c) * 64 + b) * 8 + hg * 4 + w) * 256 + s];
    }
#pragma unroll
    for (int p = 0; p < 8; ++p) {
        int idx = p * 256 + tid;
        int i = idx >> 10, c = (idx >> 9) & 1, kc = (idx >> 6) & 7, tl = idx & 63;
        ml[i][c][kc][tl] = (c ? m2 : m1)[((b * 2 + i) * 8 + kc) * 256 + t0 + tl];
    }
    float ad_r[2][2][4];
#pragma unroll
    for (int i = 0; i < 2; ++i)
#pragma unroll
        for (int c = 0; c < 2; ++c)
#pragma unroll
            for (int mi = 0; mi < 4; ++mi)
                ad_r[i][c][mi] = adb[(((i * 2 + c) * 64 + b) * 8 + h) * 256 + t0 + mi * 16 + lrow];
    __syncthreads();

    const bf16* vtp[2][2];
#pragma unroll
    for (int i = 0; i < 2; ++i)
#pragma unroll
        for (int c = 0; c < 2; ++c)
            vtp[i][c] = Vt + (((size_t)(((i * 2 + c) * 64 + b) * 8 + h)) << 13);

    f32x4 acc[2][2][4][2];
#pragma unroll
    for (int i = 0; i < 2; ++i)
#pragma unroll
        for (int c = 0; c < 2; ++c)
#pragma unroll
            for (int mi = 0; mi < 4; ++mi)
#pragma unroll
                for (int ni = 0; ni < 2; ++ni) acc[i][c][mi][ni] = (f32x4){0.f, 0.f, 0.f, 0.f};
    float lsum[2][2][4];
#pragma unroll
    for (int i = 0; i < 2; ++i)
#pragma unroll
        for (int c = 0; c < 2; ++c)
#pragma unroll
            for (int mi = 0; mi < 4; ++mi) lsum[i][c][mi] = 0.f;

    for (int kc = 0; kc < 8; ++kc) {
        int s0 = kc * 32;
        // ---- V b-frags: one b128 load each (Vt is [d][s]) ----
        bf16x8 bfr[2][2][2];
#pragma unroll
        for (int i = 0; i < 2; ++i)
#pragma unroll
            for (int c = 0; c < 2; ++c)
#pragma unroll
                for (int ni = 0; ni < 2; ++ni)
                    bfr[i][c][ni] = *(const bf16x8*)(vtp[i][c] + (size_t)(ni * 16 + lrow) * 256 + s0 + quad * 8);
#pragma unroll
        for (int i = 0; i < 2; ++i) {
#pragma unroll
            for (int c = 0; c < 2; ++c) {
                f32x4 asv0 = *(const f32x4*)&as_l[i][c][wave][s0 + quad * 8];
                f32x4 asv1 = *(const f32x4*)&as_l[i][c][wave][s0 + quad * 8 + 4];
#pragma unroll
                for (int mi = 0; mi < 4; ++mi) {
                    unsigned wb = ml[i][c][kc][mi * 16 + lrow] >> (quad * 8);
                    float ad = ad_r[i][c][mi];
                    bf16x8 af;
#pragma unroll
                    for (int j = 0; j < 8; ++j) {
                        float u = (j < 4 ? asv0[j] : asv1[j - 4]) + ad;
                        u = fmaxf(u, 0.2f * u);           // leaky_relu (log2 domain)
                        u = ((wb >> j) & 1u) ? u : 0.f;   // masked -> exp2(0)=1
                        float e = fast_exp2(u);
                        lsum[i][c][mi] += e;
                        af[j] = (bf16)e;
                    }
                    acc[i][c][mi][0] = __builtin_amdgcn_mfma_f32_16x16x32_bf16(af, bfr[i][c][0], acc[i][c][mi][0], 0, 0, 0);
                    acc[i][c][mi][1] = __builtin_amdgcn_mfma_f32_16x16x32_bf16(af, bfr[i][c][1], acc[i][c][mi][1], 0, 0, 0);
                }
            }
        }
    }

    // ---- complete row sums across quads ----
#pragma unroll
    for (int i = 0; i < 2; ++i)
#pragma unroll
        for (int c = 0; c < 2; ++c)
#pragma unroll
            for (int mi = 0; mi < 4; ++mi) {
                float l = lsum[i][c][mi];
                l += __shfl_xor(l, 16, 64);
                l += __shfl_xor(l, 32, 64);
                if (lane < 16) l_lds[i][c][wave][mi * 16 + lane] = l;
            }
    __syncthreads();

    // ---- epilogue: normalize+residual+gbias per order, then mean+PReLU --------
#pragma unroll
    for (int ni = 0; ni < 2; ++ni) {
        int dcol = h * 32 + ni * 16 + lrow;
        float gb0 = gbias[0 * 256 + dcol] + gbias[1 * 256 + dcol];   // order 0
        float gb1 = gbias[2 * 256 + dcol] + gbias[3 * 256 + dcol];   // order 1
        float pa = prelu_a[dcol];
        const bf16* r00 = vtp[0][0] + (size_t)(ni * 16 + lrow) * 256 + t0;
        const bf16* r01 = vtp[0][1] + (size_t)(ni * 16 + lrow) * 256 + t0;
        const bf16* r10 = vtp[1][0] + (size_t)(ni * 16 + lrow) * 256 + t0;
        const bf16* r11 = vtp[1][1] + (size_t)(ni * 16 + lrow) * 256 + t0;
#pragma unroll
        for (int mi = 0; mi < 4; ++mi) {
            bf16x4 rv00 = *(const bf16x4*)(r00 + mi * 16 + quad * 4);
            bf16x4 rv01 = *(const bf16x4*)(r01 + mi * 16 + quad * 4);
            bf16x4 rv10 = *(const bf16x4*)(r10 + mi * 16 + quad * 4);
            bf16x4 rv11 = *(const bf16x4*)(r11 + mi * 16 + quad * 4);
#pragma unroll
            for (int r = 0; r < 4; ++r) {
                int tl = mi * 16 + quad * 4 + r;
                int t = t0 + tl;
                float v0 = acc[0][0][mi][ni][r] * __builtin_amdgcn_rcpf(l_lds[0][0][wave][tl])
                         + acc[0][1][mi][ni][r] * __builtin_amdgcn_rcpf(l_lds[0][1][wave][tl])
                         + (float)rv00[r] + (float)rv01[r] + gb0;
                float v1 = acc[1][0][mi][ni][r] * __builtin_amdgcn_rcpf(l_lds[1][0][wave][tl])
                         + acc[1][1][mi][ni][r] * __builtin_amdgcn_rcpf(l_lds[1][1][wave][tl])
                         + (float)rv10[r] + (float)rv11[r] + gb1;
                float mn = 0.5f * (v0 + v1);
                float a0 = v0 + mn, a1 = v1 + mn;
                a0 = a0 >= 0.f ? a0 : pa * a0;
                a1 = a1 >= 0.f ? a1 : pa * a1;
                out[(((size_t)((b * 2 + 0) * 256 + t)) << 8) + dcol] = a0;
                out[(((size_t)((b * 2 + 1) * 256 + t)) << 8) + dcol] = a1;
            }
        }
    }
}

extern "C" void kernel_launch(void* const* d_in, const int* in_sizes, int n_in,
                              void* d_out, int out_size, void* d_ws, size_t ws_size,
                              hipStream_t stream) {
    const float* x       = (const float*)d_in[0];
    const int*   A       = (const int*)d_in[1];
    const float* Wp      = (const float*)d_in[2];
    const float* bp      = (const float*)d_in[3];
    const float* att_src = (const float*)d_in[4];
    const float* att_dst = (const float*)d_in[5];
    const float* gbias   = (const float*)d_in[6];
    const float* prelu_a = (const float*)d_in[7];
    float* out = (float*)d_out;

    char* ws = (char*)d_ws;
    bf16*     Wt  = (bf16*)ws;                            //   524288 B
    unsigned* m1  = (unsigned*)(ws + 524288);             //  1048576 B
    unsigned* m2  = (unsigned*)(ws + 1572864);            //  1048576 B
    float*    asb = (float*)(ws + 2621440);               //  2097152 B
    float*    adb = (float*)(ws + 4718592);               //  2097152 B
    bf16*     xb  = (bf16*)(ws + 6815744);                // 16777216 B
    bf16*     Vt  = (bf16*)(ws + 23592960);               // 16777216 B

    prep_k<<<5376, 256, 0, stream>>>(x, Wp, A, xb, Wt, m1, m2);
    dim3 gproj(128, 4, 2);
    proj_gemm<<<gproj, 256, 0, stream>>>(xb, Wt, bp, att_src, att_dst, Vt, asb, adb);
    attn_k<<<512, 256, 0, stream>>>(Vt, m1, m2, asb, adb, gbias, prelu_a, out);
}